// Round 4
// baseline (41.885 us; speedup 1.0000x reference)
//
#include <hip/hip_runtime.h>

#define NCLS 1000
#define NDF  256
#define BB   512
#define MAXOCC 64
#define O_LD 1024

#define BM 32
#define BN 64
#define BK 32
#define APAD 4   // As row = 36 floats: keeps float4 reads 16B-aligned
#define BPAD 2   // Bs row = 66 floats: keeps float2 reads 8B-aligned

// K1: fused GEMM G[m][j] = sum_k df[m][k]*fc[j][k], reading row-major operands
// and transposing into K-major LDS at staging time. Block (0,0) also computes
// the occurrence tables (occOf/occStep) needed by the combine pass.
__global__ __launch_bounds__(256) void gemm_fused(
    const float* __restrict__ df, const float* __restrict__ fc,
    const int* __restrict__ gt, int* __restrict__ occOf,
    int* __restrict__ occStep, float* __restrict__ O)
{
    __shared__ float As[2][BK][BM + APAD];
    __shared__ float Bs[2][BK][BN + BPAD];
    __shared__ int s_gt[BB];

    int tid = threadIdx.x;

    if (blockIdx.x == 0 && blockIdx.y == 0) {
        s_gt[tid] = gt[tid];
        s_gt[tid + 256] = gt[tid + 256];
        __syncthreads();
        for (int ii = tid; ii < BB; ii += 256) {
            int t = s_gt[ii];
            int n = 0;
            for (int k = 0; k <= ii; ++k) n += (s_gt[k] == t) ? 1 : 0;
            occOf[ii] = n;
            if (n <= MAXOCC) occStep[t * MAXOCC + (n - 1)] = ii;
        }
    }

    int m0 = blockIdx.y * BM;
    int j0 = blockIdx.x * BN;
    int ra = tid >> 3;            // A row within tile (m), 0..31
    int ca = (tid & 7) * 4;       // A k-col group
    int rb = tid >> 3;            // B rows rb, rb+32 (j)
    int cb = (tid & 7) * 4;
    int tx = tid & 31;            // j pairs
    int ty = tid >> 5;            // m quads

    const float* dfp  = df + (size_t)(m0 + ra) * NDF + ca;
    int jb0 = j0 + rb, jb1 = j0 + rb + 32;
    const float* fcp0 = fc + (size_t)jb0 * NDF + cb;
    const float* fcp1 = fc + (size_t)jb1 * NDF + cb;
    bool v0 = jb0 < NCLS, v1 = jb1 < NCLS;
    float4 zero4 = make_float4(0.f, 0.f, 0.f, 0.f);

    float4 va  = *(const float4*)dfp;
    float4 vb0 = v0 ? *(const float4*)fcp0 : zero4;
    float4 vb1 = v1 ? *(const float4*)fcp1 : zero4;

    As[0][ca + 0][ra] = va.x; As[0][ca + 1][ra] = va.y;
    As[0][ca + 2][ra] = va.z; As[0][ca + 3][ra] = va.w;
    Bs[0][cb + 0][rb] = vb0.x; Bs[0][cb + 1][rb] = vb0.y;
    Bs[0][cb + 2][rb] = vb0.z; Bs[0][cb + 3][rb] = vb0.w;
    Bs[0][cb + 0][rb + 32] = vb1.x; Bs[0][cb + 1][rb + 32] = vb1.y;
    Bs[0][cb + 2][rb + 32] = vb1.z; Bs[0][cb + 3][rb + 32] = vb1.w;
    __syncthreads();

    float acc[4][2] = {};
    const int NCHUNK = NDF / BK;  // 8
    for (int c = 0; c < NCHUNK; ++c) {
        int cur = c & 1, nxt = cur ^ 1;
        if (c + 1 < NCHUNK) {
            int k0 = (c + 1) * BK;
            va  = *(const float4*)(dfp + k0);
            vb0 = v0 ? *(const float4*)(fcp0 + k0) : zero4;
            vb1 = v1 ? *(const float4*)(fcp1 + k0) : zero4;
        }
#pragma unroll
        for (int kk = 0; kk < BK; ++kk) {
            float4 a = *(const float4*)&As[cur][kk][ty * 4];
            float2 b = *(const float2*)&Bs[cur][kk][tx * 2];
            acc[0][0] += a.x * b.x; acc[0][1] += a.x * b.y;
            acc[1][0] += a.y * b.x; acc[1][1] += a.y * b.y;
            acc[2][0] += a.z * b.x; acc[2][1] += a.z * b.y;
            acc[3][0] += a.w * b.x; acc[3][1] += a.w * b.y;
        }
        if (c + 1 < NCHUNK) {
            As[nxt][ca + 0][ra] = va.x; As[nxt][ca + 1][ra] = va.y;
            As[nxt][ca + 2][ra] = va.z; As[nxt][ca + 3][ra] = va.w;
            Bs[nxt][cb + 0][rb] = vb0.x; Bs[nxt][cb + 1][rb] = vb0.y;
            Bs[nxt][cb + 2][rb] = vb0.z; Bs[nxt][cb + 3][rb] = vb0.w;
            Bs[nxt][cb + 0][rb + 32] = vb1.x; Bs[nxt][cb + 1][rb + 32] = vb1.y;
            Bs[nxt][cb + 2][rb + 32] = vb1.z; Bs[nxt][cb + 3][rb + 32] = vb1.w;
            __syncthreads();
        }
    }
#pragma unroll
    for (int r = 0; r < 4; ++r) {
        *(float2*)&O[(size_t)(m0 + ty * 4 + r) * O_LD + j0 + tx * 2] =
            make_float2(acc[r][0], acc[r][1]);
    }
}

// K2: scores[i][j] = G[i][j]-G[i][t]
//   + 0.05 * sum_{m=2..n} ((m-1)/(m*n)) * (h_m[j]-h_m[t])^2,
// h_m[j] = G[s_m][j] - (1/m)*sum_{m'<=m} G[s_m'][j]. Two j per thread (float2).
__global__ void combine_kernel(const int* __restrict__ gt, const int* __restrict__ occOf,
                               const int* __restrict__ occStep, const float* __restrict__ O,
                               float* __restrict__ out) {
    int i = blockIdx.y;
    int j = blockIdx.x * 512 + threadIdx.x * 2;
    if (j >= NCLS) return;
    int t = gt[i];
    int n = occOf[i];
    const float* Grow = O + (size_t)i * O_LD;
    float2 gv = *(const float2*)&Grow[j];
    float gtv = Grow[t];
    float gx = gv.x - gtv, gy = gv.y - gtv;
    float qx = 0.f, qy = 0.f;
    if (n >= 2) {
        float Sx = 0.f, Sy = 0.f, St = 0.f;
        for (int m = 1; m <= n; ++m) {
            int s = occStep[t * MAXOCC + (m - 1)];
            float2 Gsj = *(const float2*)&O[(size_t)s * O_LD + j];
            float Gst = O[(size_t)s * O_LD + t];
            Sx += Gsj.x; Sy += Gsj.y; St += Gst;
            if (m >= 2) {
                float inv_m = 1.f / (float)m;
                float ht = Gst - St * inv_m;
                float hx = (Gsj.x - Sx * inv_m) - ht;
                float hy = (Gsj.y - Sy * inv_m) - ht;
                float coef = (float)(m - 1) * inv_m / (float)n;
                qx += coef * hx * hx;
                qy += coef * hy * hy;
            }
        }
    }
    float ox = gx + 0.05f * qx;   // 0.5*ALP = 0.05
    float oy = gy + 0.05f * qy;
    if (j + 1 < NCLS) {
        *(float2*)&out[(size_t)i * NCLS + j] = make_float2(ox, oy);
    } else {
        out[(size_t)i * NCLS + j] = ox;
    }
}

extern "C" void kernel_launch(void* const* d_in, const int* in_sizes, int n_in,
                              void* d_out, int out_size, void* d_ws, size_t ws_size,
                              hipStream_t stream) {
    const float* df = (const float*)d_in[0];
    const int*   gt = (const int*)d_in[1];
    const float* fc = (const float*)d_in[2];
    float* out = (float*)d_out;

    char* ws = (char*)d_ws;
    int*   occOf   = (int*)ws;                       // 2048 B (slot 4096)
    int*   occStep = (int*)(ws + 4096);              // 256000 B (slot 262144)
    float* O       = (float*)(ws + 4096 + 262144);   // 512*1024*4 = 2 MB
    // total ~2.3 MB of ws

    gemm_fused<<<dim3(16, 16), 256, 0, stream>>>(df, fc, gt, occOf, occStep, O);
    combine_kernel<<<dim3(2, BB), 256, 0, stream>>>(gt, occOf, occStep, O, out);
}

// Round 5
// 21.112 us; speedup vs baseline: 1.9840x; 1.9840x over previous
//
#include <hip/hip_runtime.h>

#define NCLS 1000
#define NDF  256
#define BB   512
#define MAXOCC 64
#define O_LD 1024

#define BM 32
#define BN 64
#define BK 32
#define NCHUNK (NDF / BK)   // 8

typedef __attribute__((ext_vector_type(8))) short short8;
typedef __attribute__((ext_vector_type(4))) float floatx4;

static __device__ __forceinline__ unsigned short f2bf(float f) {
    unsigned int u = __float_as_uint(f);
    u += 0x7FFFu + ((u >> 16) & 1u);   // RNE
    return (unsigned short)(u >> 16);
}

// K1: occurrence tables (verified in R2-R4). occOf[i] = 1-based occurrence
// index of gt[i] within gt[0..i]; occStep[t*MAXOCC+m-1] = step of m-th occ of t.
__global__ void occ_kernel(const int* __restrict__ gt, int* __restrict__ occOf,
                           int* __restrict__ occStep) {
    __shared__ int s_gt[BB];
    int tid = threadIdx.x;
    s_gt[tid] = gt[tid];
    __syncthreads();
    int t = s_gt[tid];
    int n = 0;
    for (int k = 0; k <= tid; ++k) n += (s_gt[k] == t) ? 1 : 0;
    occOf[tid] = n;
    if (n <= MAXOCC) occStep[t * MAXOCC + (n - 1)] = tid;
}

// K2: G[m][j] = sum_k df[m][k]*fc[j][k] via bf16 MFMA, fp32 accumulate.
// Staging converts fp32->bf16 into double-buffered LDS. Block-uniform FULL
// split keeps global loads unconditional for 15/16 j-blocks.
template <bool FULL>
static __device__ __forceinline__ void run_pipe(
    const float* __restrict__ ap, const float* __restrict__ bp, bool bok,
    unsigned short (&Ah)[2][BM][BK], unsigned short (&Bh)[2][BN][BK],
    int arow, int ak, int brow, int bk,
    int r16, int c32, int lr, int lk,
    floatx4& acc0, floatx4& acc1)
{
    float4 va = *(const float4*)ap;
    float4 vb0, vb1;
    if (FULL || bok) { vb0 = *(const float4*)bp; vb1 = *(const float4*)(bp + 4); }
    else { vb0 = make_float4(0.f, 0.f, 0.f, 0.f); vb1 = vb0; }

    *(ushort4*)&Ah[0][arow][ak] =
        make_ushort4(f2bf(va.x), f2bf(va.y), f2bf(va.z), f2bf(va.w));
    *(ushort4*)&Bh[0][brow][bk] =
        make_ushort4(f2bf(vb0.x), f2bf(vb0.y), f2bf(vb0.z), f2bf(vb0.w));
    *(ushort4*)&Bh[0][brow][bk + 4] =
        make_ushort4(f2bf(vb1.x), f2bf(vb1.y), f2bf(vb1.z), f2bf(vb1.w));
    __syncthreads();

    for (int c = 0; c < NCHUNK; ++c) {
        int cur = c & 1;
        float4 na, nb0, nb1;
        if (c + 1 < NCHUNK) {
            int k0 = (c + 1) * BK;
            na = *(const float4*)(ap + k0);
            if (FULL || bok) {
                nb0 = *(const float4*)(bp + k0);
                nb1 = *(const float4*)(bp + k0 + 4);
            } else {
                nb0 = make_float4(0.f, 0.f, 0.f, 0.f); nb1 = nb0;
            }
        }
        short8 a  = *(const short8*)&Ah[cur][r16 + lr][lk];
        short8 b0 = *(const short8*)&Bh[cur][c32 + lr][lk];
        short8 b1 = *(const short8*)&Bh[cur][c32 + 16 + lr][lk];
        acc0 = __builtin_amdgcn_mfma_f32_16x16x32_bf16(a, b0, acc0, 0, 0, 0);
        acc1 = __builtin_amdgcn_mfma_f32_16x16x32_bf16(a, b1, acc1, 0, 0, 0);
        if (c + 1 < NCHUNK) {
            int nxt = cur ^ 1;
            *(ushort4*)&Ah[nxt][arow][ak] =
                make_ushort4(f2bf(na.x), f2bf(na.y), f2bf(na.z), f2bf(na.w));
            *(ushort4*)&Bh[nxt][brow][bk] =
                make_ushort4(f2bf(nb0.x), f2bf(nb0.y), f2bf(nb0.z), f2bf(nb0.w));
            *(ushort4*)&Bh[nxt][brow][bk + 4] =
                make_ushort4(f2bf(nb1.x), f2bf(nb1.y), f2bf(nb1.z), f2bf(nb1.w));
            __syncthreads();
        }
    }
}

__global__ __launch_bounds__(256) void gemm_mfma(const float* __restrict__ df,
                                                 const float* __restrict__ fc,
                                                 float* __restrict__ O) {
    __shared__ unsigned short Ah[2][BM][BK];
    __shared__ unsigned short Bh[2][BN][BK];
    int tid = threadIdx.x;
    int m0 = blockIdx.y * BM;
    int j0 = blockIdx.x * BN;

    // staging coords: A 32x32 (4 floats/thread), B 64x32 (8 floats/thread)
    int arow = tid >> 3, ak = (tid & 7) * 4;
    int brow = tid >> 2, bk = (tid & 3) * 8;
    const float* ap = df + (size_t)(m0 + arow) * NDF + ak;
    const float* bp = fc + (size_t)(j0 + brow) * NDF + bk;
    bool bok = (j0 + brow) < NCLS;

    // fragment coords: wave w owns rows r16..r16+15, cols c32..c32+31
    int lane = tid & 63, w = tid >> 6;
    int r16 = (w & 1) * 16, c32 = (w >> 1) * 32;
    int lr = lane & 15, lk = (lane >> 4) * 8;

    floatx4 acc0 = {0.f, 0.f, 0.f, 0.f}, acc1 = {0.f, 0.f, 0.f, 0.f};

    if (j0 + BN <= NCLS) {
        run_pipe<true>(ap, bp, bok, Ah, Bh, arow, ak, brow, bk,
                       r16, c32, lr, lk, acc0, acc1);
    } else {
        run_pipe<false>(ap, bp, bok, Ah, Bh, arow, ak, brow, bk,
                        r16, c32, lr, lk, acc0, acc1);
    }

    // C/D layout: col = lane&15, row = (lane>>4)*4 + reg   [m89-verified]
    int orow = m0 + r16 + (lane >> 4) * 4;
    int ocol = j0 + c32 + lr;
#pragma unroll
    for (int r = 0; r < 4; ++r) {
        O[(size_t)(orow + r) * O_LD + ocol]      = acc0[r];
        O[(size_t)(orow + r) * O_LD + ocol + 16] = acc1[r];
    }
}

// K3: scores[i][j] = G[i][j]-G[i][t]
//   + 0.05 * sum_{m=2..n} ((m-1)/(m*n)) * (h_m[j]-h_m[t])^2,
// h_m[j] = G[s_m][j] - (1/m)*sum_{m'<=m} G[s_m'][j]. Two j per thread.
__global__ void combine_kernel(const int* __restrict__ gt, const int* __restrict__ occOf,
                               const int* __restrict__ occStep, const float* __restrict__ O,
                               float* __restrict__ out) {
    int i = blockIdx.y;
    int j = blockIdx.x * 512 + threadIdx.x * 2;
    if (j >= NCLS) return;
    int t = gt[i];
    int n = occOf[i];
    const float* Grow = O + (size_t)i * O_LD;
    float2 gv = *(const float2*)&Grow[j];
    float gtv = Grow[t];
    float gx = gv.x - gtv, gy = gv.y - gtv;
    float qx = 0.f, qy = 0.f;
    if (n >= 2) {
        float Sx = 0.f, Sy = 0.f, St = 0.f;
        for (int m = 1; m <= n; ++m) {
            int s = occStep[t * MAXOCC + (m - 1)];
            float2 Gsj = *(const float2*)&O[(size_t)s * O_LD + j];
            float Gst = O[(size_t)s * O_LD + t];
            Sx += Gsj.x; Sy += Gsj.y; St += Gst;
            if (m >= 2) {
                float inv_m = 1.f / (float)m;
                float ht = Gst - St * inv_m;
                float hx = (Gsj.x - Sx * inv_m) - ht;
                float hy = (Gsj.y - Sy * inv_m) - ht;
                float coef = (float)(m - 1) * inv_m / (float)n;
                qx += coef * hx * hx;
                qy += coef * hy * hy;
            }
        }
    }
    float ox = gx + 0.05f * qx;   // 0.5*ALP = 0.05
    float oy = gy + 0.05f * qy;
    if (j + 1 < NCLS) {
        *(float2*)&out[(size_t)i * NCLS + j] = make_float2(ox, oy);
    } else {
        out[(size_t)i * NCLS + j] = ox;
    }
}

extern "C" void kernel_launch(void* const* d_in, const int* in_sizes, int n_in,
                              void* d_out, int out_size, void* d_ws, size_t ws_size,
                              hipStream_t stream) {
    const float* df = (const float*)d_in[0];
    const int*   gt = (const int*)d_in[1];
    const float* fc = (const float*)d_in[2];
    float* out = (float*)d_out;

    char* ws = (char*)d_ws;
    int*   occOf   = (int*)ws;                       // 2048 B (slot 4096)
    int*   occStep = (int*)(ws + 4096);              // 256000 B (slot 262144)
    float* O       = (float*)(ws + 4096 + 262144);   // 512*1024*4 = 2 MB

    occ_kernel<<<1, BB, 0, stream>>>(gt, occOf, occStep);
    gemm_mfma<<<dim3(16, 16), 256, 0, stream>>>(df, fc, O);
    combine_kernel<<<dim3(2, BB), 256, 0, stream>>>(gt, occOf, occStep, O, out);
}